// Round 16
// baseline (826.936 us; speedup 1.0000x reference)
//
#include <hip/hip_runtime.h>
#include <cstdint>
#include <cstddef>

// LESSON (R13/R14): __has_builtin(__builtin_amdgcn_*) is FALSE in hipcc's HOST
// pass — never use it to select kernel launches host-side.

typedef _Float16 h2 __attribute__((ext_vector_type(2)));
typedef short bf16x8 __attribute__((ext_vector_type(8)));
typedef float f32x4 __attribute__((ext_vector_type(4)));

__device__ __forceinline__ float sigf(float x) { return 1.0f / (1.0f + __expf(-x)); }
__device__ __forceinline__ float tanhfast(float x) {
  float e = __expf(-2.0f * fabsf(x));
  float t = (1.0f - e) / (1.0f + e);
  return copysignf(t, x);
}
__device__ __forceinline__ h2 cvt2(float a, float b) {
  h2 r; r.x = (_Float16)a; r.y = (_Float16)b; return r;
}
__device__ __forceinline__ h2 bch2(unsigned int u) { return __builtin_bit_cast(h2, u); }
__device__ __forceinline__ unsigned int bcu(h2 v) { return __builtin_bit_cast(unsigned int, v); }
__device__ __forceinline__ unsigned short f2bf(float f) {
  unsigned int u = __float_as_uint(f);
  u = (u + 0x7fffu + ((u >> 16) & 1u)) >> 16;
  return (unsigned short)u;
}

__device__ __forceinline__ float fdot2f(h2 a, h2 b, float c) {
#if __has_builtin(__builtin_amdgcn_fdot2)
  return __builtin_amdgcn_fdot2(a, b, c, false);
#else
  return fmaf((float)a.x, (float)b.x, fmaf((float)a.y, (float)b.y, c));
#endif
}

// ---------------- fused f32 -> bf16 convert for ALL weights (1 launch) ---------
__global__ void convert_all(const float* __restrict__ s0, ushort* __restrict__ d0,
                            const float* __restrict__ s1, ushort* __restrict__ d1,
                            const float* __restrict__ s2, ushort* __restrict__ d2,
                            const float* __restrict__ s3, ushort* __restrict__ d3,
                            const float* __restrict__ s4, ushort* __restrict__ d4,
                            const float* __restrict__ s5, ushort* __restrict__ d5) {
  int i = blockIdx.x * 256 + threadIdx.x;
  if (i < 589824) { d0[i] = f2bf(s0[i]); return; }
  i -= 589824;
  if (i < 196608) { d1[i] = f2bf(s1[i]); return; }
  i -= 196608;
  if (i < 393216) { d2[i] = f2bf(s2[i]); return; }
  i -= 393216;
  if (i < 393216) { d3[i] = f2bf(s3[i]); return; }
  i -= 393216;
  if (i < 262144) { d4[i] = f2bf(s4[i]); return; }
  i -= 262144;
  if (i < 65536) d5[i] = f2bf(s5[i]);
}

// ---------------- part encoder ----------------
__global__ void part_encoder(const float* __restrict__ parts, const float* __restrict__ Wpe1,
                             const float* __restrict__ bpe1, const float* __restrict__ Wpe2,
                             const float* __restrict__ bpe2, const float* __restrict__ pos,
                             float* __restrict__ x, ushort* __restrict__ xb) {
  __shared__ float prow[16];
  __shared__ float pe1[128];
  int row = blockIdx.x;
  int s = row & 255;
  int tid = threadIdx.x;  // 128
  if (tid < 16) prow[tid] = parts[row * 16 + tid];
  __syncthreads();
  float a = bpe1[tid];
#pragma unroll
  for (int k = 0; k < 16; ++k) a = fmaf(prow[k], Wpe1[tid * 16 + k], a);
  pe1[tid] = fmaxf(a, 0.0f);
  __syncthreads();
  float a2 = bpe2[tid];
  for (int k = 0; k < 128; ++k) a2 = fmaf(pe1[k], Wpe2[tid * 128 + k], a2);
  x[(size_t)row * 256 + tid] = a2;
  xb[(size_t)row * 256 + tid] = f2bf(a2);
  if (tid < 64) {
    float p = pos[s * 64 + tid];
    x[(size_t)row * 256 + 128 + tid] = p;
    xb[(size_t)row * 256 + 128 + tid] = f2bf(p);
    x[(size_t)row * 256 + 192 + tid] = 0.0f;
    xb[(size_t)row * 256 + 192 + tid] = 0;
  }
}

// ---------------- MFMA bf16 GEMM, 1-wave blocks (16 rows x 64 cols) ------------
// OUT: 0 = f32; 1 = bf16; 3 = f32 TRANSPOSED penT. GATHER: A-row indirection
// through ts (teacher-forced dec_in: row m -> (t=m>>3,b=m&7); t==0 -> zeros).
template <int ACT, int OUT, int GATHER>
__global__ __launch_bounds__(64) void gemm_bf16(
    const ushort* __restrict__ A, const ushort* __restrict__ Wt,
    const float* __restrict__ bias1, const float* __restrict__ bias2,
    void* __restrict__ Cout, int N, int K, const int* __restrict__ ts) {
  int lane = threadIdx.x;          // 0..63
  int m0 = blockIdx.y * 16;
  int n0 = blockIdx.x * 64;
  int r15 = lane & 15;
  int kg = lane >> 4;
  f32x4 acc0 = {0.f, 0.f, 0.f, 0.f}, acc1 = acc0, acc2 = acc0, acc3 = acc0;
  const ushort* arow;
  bool zeroA = false;
  if (GATHER) {
    int m = m0 + r15;
    int t = m >> 3, b = m & 7;
    if (t == 0) { zeroA = true; arow = A; }
    else {
      int sidx = ts[b * 256 + t - 1];
      arow = A + (size_t)(b * 256 + sidx) * 256 + kg * 8;
    }
  } else {
    arow = A + (size_t)(m0 + r15) * K + kg * 8;
  }
  const ushort* w0 = Wt + (size_t)(n0 + r15) * K + kg * 8;
  const ushort* w1 = w0 + (size_t)16 * K;
  const ushort* w2 = w0 + (size_t)32 * K;
  const ushort* w3 = w0 + (size_t)48 * K;
  for (int k0 = 0; k0 < K; k0 += 32) {
    bf16x8 af;
    if (GATHER && zeroA) af = (bf16x8){0, 0, 0, 0, 0, 0, 0, 0};
    else af = *(const bf16x8*)(arow + k0);
    bf16x8 b0 = *(const bf16x8*)(w0 + k0);
    bf16x8 b1 = *(const bf16x8*)(w1 + k0);
    bf16x8 b2 = *(const bf16x8*)(w2 + k0);
    bf16x8 b3 = *(const bf16x8*)(w3 + k0);
    acc0 = __builtin_amdgcn_mfma_f32_16x16x32_bf16(af, b0, acc0, 0, 0, 0);
    acc1 = __builtin_amdgcn_mfma_f32_16x16x32_bf16(af, b1, acc1, 0, 0, 0);
    acc2 = __builtin_amdgcn_mfma_f32_16x16x32_bf16(af, b2, acc2, 0, 0, 0);
    acc3 = __builtin_amdgcn_mfma_f32_16x16x32_bf16(af, b3, acc3, 0, 0, 0);
  }
#pragma unroll
  for (int nn = 0; nn < 4; ++nn) {
    f32x4 a = (nn == 0) ? acc0 : (nn == 1) ? acc1 : (nn == 2) ? acc2 : acc3;
    int n = n0 + nn * 16 + r15;
    float bsum = bias1[n] + (bias2 ? bias2[n] : 0.0f);
    if (OUT == 3) {
      int b = m0 >> 8;
      int mloc = (m0 & 255) + kg * 4;
      float4 o4 = {a[0] + bsum, a[1] + bsum, a[2] + bsum, a[3] + bsum};
      *(float4*)&((float*)Cout)[((size_t)(b * 256 + n)) * 256 + mloc] = o4;
    } else {
#pragma unroll
      for (int r = 0; r < 4; ++r) {
        int m = m0 + kg * 4 + r;
        float v = a[r] + bsum;
        if (ACT == 1) v = fmaxf(v, 0.0f);
        if (OUT == 1)
          ((ushort*)Cout)[(size_t)m * N + n] = f2bf(v);
        else
          ((float*)Cout)[(size_t)m * N + n] = v;
      }
    }
  }
}

// ---------------- fused GEMM (N=256) + residual LayerNorm ----------------
// Block = 256 thr (4 waves); block owns 16 FULL rows. Wave w computes cols
// w*64..w*64+63 into LDS osm[16][257]; then the block LNs its rows in place:
// thread (row=tid>>4, j=tid&15) handles cols j*16..+15, 16-lane shfl reduce.
// Writes xbuf (f32) + xbf (bf16). Eliminates obuf + separate ln_residual pass.
__global__ __launch_bounds__(256) void gemm_ln(
    const ushort* __restrict__ A, const ushort* __restrict__ Wt,
    const float* __restrict__ bias1, float* __restrict__ x,
    const float* __restrict__ g, const float* __restrict__ bt,
    ushort* __restrict__ xb, int K) {
  __shared__ float osm[16][257];
  int tid = threadIdx.x;
  int w = tid >> 6, lane = tid & 63;
  int m0 = blockIdx.x * 16;
  int n0 = w * 64;
  int r15 = lane & 15, kg = lane >> 4;
  f32x4 acc0 = {0.f, 0.f, 0.f, 0.f}, acc1 = acc0, acc2 = acc0, acc3 = acc0;
  const ushort* arow = A + (size_t)(m0 + r15) * K + kg * 8;
  const ushort* w0 = Wt + (size_t)(n0 + r15) * K + kg * 8;
  const ushort* w1 = w0 + (size_t)16 * K;
  const ushort* w2 = w0 + (size_t)32 * K;
  const ushort* w3 = w0 + (size_t)48 * K;
  for (int k0 = 0; k0 < K; k0 += 32) {
    bf16x8 af = *(const bf16x8*)(arow + k0);
    bf16x8 b0 = *(const bf16x8*)(w0 + k0);
    bf16x8 b1 = *(const bf16x8*)(w1 + k0);
    bf16x8 b2 = *(const bf16x8*)(w2 + k0);
    bf16x8 b3 = *(const bf16x8*)(w3 + k0);
    acc0 = __builtin_amdgcn_mfma_f32_16x16x32_bf16(af, b0, acc0, 0, 0, 0);
    acc1 = __builtin_amdgcn_mfma_f32_16x16x32_bf16(af, b1, acc1, 0, 0, 0);
    acc2 = __builtin_amdgcn_mfma_f32_16x16x32_bf16(af, b2, acc2, 0, 0, 0);
    acc3 = __builtin_amdgcn_mfma_f32_16x16x32_bf16(af, b3, acc3, 0, 0, 0);
  }
#pragma unroll
  for (int nn = 0; nn < 4; ++nn) {
    f32x4 a = (nn == 0) ? acc0 : (nn == 1) ? acc1 : (nn == 2) ? acc2 : acc3;
    int col = n0 + nn * 16 + r15;
    float bsum = bias1[col];
#pragma unroll
    for (int r = 0; r < 4; ++r) osm[kg * 4 + r][col] = a[r] + bsum;
  }
  __syncthreads();
  // ---- LN phase ----
  int row = tid >> 4, j = tid & 15;
  size_t xoff = (size_t)(m0 + row) * 256 + j * 16;
  float4 xv0 = *(const float4*)&x[xoff];
  float4 xv1 = *(const float4*)&x[xoff + 4];
  float4 xv2 = *(const float4*)&x[xoff + 8];
  float4 xv3 = *(const float4*)&x[xoff + 12];
  float e0 = xv0.x + osm[row][j * 16 + 0], e1 = xv0.y + osm[row][j * 16 + 1];
  float e2 = xv0.z + osm[row][j * 16 + 2], e3 = xv0.w + osm[row][j * 16 + 3];
  float e4 = xv1.x + osm[row][j * 16 + 4], e5 = xv1.y + osm[row][j * 16 + 5];
  float e6 = xv1.z + osm[row][j * 16 + 6], e7 = xv1.w + osm[row][j * 16 + 7];
  float e8 = xv2.x + osm[row][j * 16 + 8], e9 = xv2.y + osm[row][j * 16 + 9];
  float e10 = xv2.z + osm[row][j * 16 + 10], e11 = xv2.w + osm[row][j * 16 + 11];
  float e12 = xv3.x + osm[row][j * 16 + 12], e13 = xv3.y + osm[row][j * 16 + 13];
  float e14 = xv3.z + osm[row][j * 16 + 14], e15 = xv3.w + osm[row][j * 16 + 15];
  float s = ((e0 + e1) + (e2 + e3)) + ((e4 + e5) + (e6 + e7)) +
            ((e8 + e9) + (e10 + e11)) + ((e12 + e13) + (e14 + e15));
  float q = ((e0 * e0 + e1 * e1) + (e2 * e2 + e3 * e3)) +
            ((e4 * e4 + e5 * e5) + (e6 * e6 + e7 * e7)) +
            ((e8 * e8 + e9 * e9) + (e10 * e10 + e11 * e11)) +
            ((e12 * e12 + e13 * e13) + (e14 * e14 + e15 * e15));
#pragma unroll
  for (int off = 1; off <= 8; off <<= 1) {
    s += __shfl_xor(s, off);
    q += __shfl_xor(q, off);
  }
  float mean = s * (1.0f / 256.0f);
  float var = q * (1.0f / 256.0f) - mean * mean;
  float inv = rsqrtf(var + 1e-5f);
  const float* gp = g + j * 16;
  const float* bp2 = bt + j * 16;
  float y0 = (e0 - mean) * inv * gp[0] + bp2[0];
  float y1 = (e1 - mean) * inv * gp[1] + bp2[1];
  float y2 = (e2 - mean) * inv * gp[2] + bp2[2];
  float y3 = (e3 - mean) * inv * gp[3] + bp2[3];
  float y4 = (e4 - mean) * inv * gp[4] + bp2[4];
  float y5 = (e5 - mean) * inv * gp[5] + bp2[5];
  float y6 = (e6 - mean) * inv * gp[6] + bp2[6];
  float y7 = (e7 - mean) * inv * gp[7] + bp2[7];
  float y8 = (e8 - mean) * inv * gp[8] + bp2[8];
  float y9 = (e9 - mean) * inv * gp[9] + bp2[9];
  float y10 = (e10 - mean) * inv * gp[10] + bp2[10];
  float y11 = (e11 - mean) * inv * gp[11] + bp2[11];
  float y12 = (e12 - mean) * inv * gp[12] + bp2[12];
  float y13 = (e13 - mean) * inv * gp[13] + bp2[13];
  float y14 = (e14 - mean) * inv * gp[14] + bp2[14];
  float y15 = (e15 - mean) * inv * gp[15] + bp2[15];
  *(float4*)&x[xoff] = make_float4(y0, y1, y2, y3);
  *(float4*)&x[xoff + 4] = make_float4(y4, y5, y6, y7);
  *(float4*)&x[xoff + 8] = make_float4(y8, y9, y10, y11);
  *(float4*)&x[xoff + 12] = make_float4(y12, y13, y14, y15);
  ushort4 u0, u1, u2, u3;
  u0.x = f2bf(y0); u0.y = f2bf(y1); u0.z = f2bf(y2); u0.w = f2bf(y3);
  u1.x = f2bf(y4); u1.y = f2bf(y5); u1.z = f2bf(y6); u1.w = f2bf(y7);
  u2.x = f2bf(y8); u2.y = f2bf(y9); u2.z = f2bf(y10); u2.w = f2bf(y11);
  u3.x = f2bf(y12); u3.y = f2bf(y13); u3.z = f2bf(y14); u3.w = f2bf(y15);
  *(ushort4*)&xb[xoff] = u0;
  *(ushort4*)&xb[xoff + 4] = u1;
  *(ushort4*)&xb[xoff + 8] = u2;
  *(ushort4*)&xb[xoff + 12] = u3;
}

// ---------------- attention (f32 in, bf16 out) ----------------
__global__ void attn_kernel(const float* __restrict__ qkv, ushort* __restrict__ attout) {
  extern __shared__ float sm[];
  float* kl = sm;
  float* ql = sm + 256 * 33;
  float* sc = sm + 256 * 33 + 32 * 33;
  int qt = blockIdx.x, h = blockIdx.y, b = blockIdx.z;
  int tid = threadIdx.x;  // 256
  {
    int j = tid;
    const float* src = qkv + (size_t)(b * 256 + j) * 768 + 256 + h * 32;
#pragma unroll
    for (int d = 0; d < 32; d += 4) {
      float4 v = *(const float4*)(src + d);
      kl[j * 33 + d] = v.x; kl[j * 33 + d + 1] = v.y; kl[j * 33 + d + 2] = v.z; kl[j * 33 + d + 3] = v.w;
    }
  }
  {
    int i = tid >> 3, d4 = (tid & 7) * 4;
    const float* src = qkv + (size_t)(b * 256 + qt * 32 + i) * 768 + h * 32;
    float4 v = *(const float4*)(src + d4);
    ql[i * 33 + d4] = v.x; ql[i * 33 + d4 + 1] = v.y; ql[i * 33 + d4 + 2] = v.z; ql[i * 33 + d4 + 3] = v.w;
  }
  __syncthreads();
  int i = tid >> 3, c = tid & 7;
  const float scale = 0.17677669529663687f;
  float sv[32];
  float mx = -1e30f;
  for (int jj = 0; jj < 32; ++jj) {
    int j = jj * 8 + c;
    float s = 0.0f;
#pragma unroll
    for (int d = 0; d < 32; ++d) s = fmaf(ql[i * 33 + d], kl[j * 33 + d], s);
    s *= scale;
    sv[jj] = s;
    mx = fmaxf(mx, s);
  }
  mx = fmaxf(mx, __shfl_xor(mx, 1));
  mx = fmaxf(mx, __shfl_xor(mx, 2));
  mx = fmaxf(mx, __shfl_xor(mx, 4));
  float sum = 0.0f;
  for (int jj = 0; jj < 32; ++jj) {
    float p = __expf(sv[jj] - mx);
    sc[i * 257 + jj * 8 + c] = p;
    sum += p;
  }
  sum += __shfl_xor(sum, 1);
  sum += __shfl_xor(sum, 2);
  sum += __shfl_xor(sum, 4);
  float inv = 1.0f / sum;
  __syncthreads();
  float a0 = 0, a1 = 0, a2 = 0, a3 = 0;
  int d0 = c * 4;
  const float* vbase = qkv + 512 + h * 32 + d0;
  for (int j = 0; j < 256; ++j) {
    float p = sc[i * 257 + j];
    float4 v = *(const float4*)(vbase + (size_t)(b * 256 + j) * 768);
    a0 = fmaf(p, v.x, a0); a1 = fmaf(p, v.y, a1); a2 = fmaf(p, v.z, a2); a3 = fmaf(p, v.w, a3);
  }
  int orow = b * 256 + qt * 32 + i;
  ushort4 o4;
  o4.x = f2bf(a0 * inv); o4.y = f2bf(a1 * inv); o4.z = f2bf(a2 * inv); o4.w = f2bf(a3 * inv);
  *(ushort4*)&attout[(size_t)orow * 256 + h * 32 + d0] = o4;
}

// ---------------- LSTM scan v512 (PROVEN; single-CU bf16 storage floor) -------
__global__ __attribute__((amdgpu_flat_work_group_size(512, 512), amdgpu_waves_per_eu(1, 1)))
void lstm_scan512(const float* __restrict__ Xw, const float* __restrict__ Whh,
                  ushort* __restrict__ dec_out) {
  extern __shared__ char smem[];
  uint4* wlds = (uint4*)smem;                 // [8][1024] uint4 = 128 KB
  h2* hbuf = (h2*)(smem + 131072);            // [2][128] h2
  int b = blockIdx.x;
  int t0 = threadIdx.x;        // 0..511
  int u = t0 >> 1, p = t0 & 1;
  int rA = u + 256 * p;
  int rB = u + 512 + 256 * p;

  h2 w0[96], w1[96];
  {
    const float4* sA = (const float4*)(Whh + (size_t)rA * 256);
    const float4* sB = (const float4*)(Whh + (size_t)rB * 256);
#pragma unroll
    for (int k = 0; k < 48; ++k) {
      float4 v = sA[k];
      w0[2 * k] = cvt2(v.x, v.y);
      w0[2 * k + 1] = cvt2(v.z, v.w);
    }
#pragma unroll
    for (int k = 0; k < 48; ++k) {
      float4 v = sB[k];
      w1[2 * k] = cvt2(v.x, v.y);
      w1[2 * k + 1] = cvt2(v.z, v.w);
    }
#pragma unroll
    for (int qc = 0; qc < 8; ++qc) {
      float4 vA0 = sA[48 + 2 * qc], vA1 = sA[48 + 2 * qc + 1];
      float4 vB0 = sB[48 + 2 * qc], vB1 = sB[48 + 2 * qc + 1];
      uint4 uA, uB;
      uA.x = bcu(cvt2(vA0.x, vA0.y)); uA.y = bcu(cvt2(vA0.z, vA0.w));
      uA.z = bcu(cvt2(vA1.x, vA1.y)); uA.w = bcu(cvt2(vA1.z, vA1.w));
      uB.x = bcu(cvt2(vB0.x, vB0.y)); uB.y = bcu(cvt2(vB0.z, vB0.w));
      uB.z = bcu(cvt2(vB1.x, vB1.y)); uB.w = bcu(cvt2(vB1.z, vB1.w));
      wlds[qc * 1024 + rA] = uA;
      wlds[qc * 1024 + rB] = uB;
    }
  }
  if (t0 < 128) ((uint4*)hbuf)[t0 & 63] = make_uint4(0, 0, 0, 0);
  float c = 0.0f;
  float xnA = Xw[(size_t)b * 1024 + rA];
  float xnB = Xw[(size_t)b * 1024 + rB];
  __syncthreads();

  for (int t = 0; t < 256; ++t) {
    float xwA = xnA, xwB = xnB;
    if (t < 255) {
      const float* xp = Xw + (size_t)((t + 1) * 8 + b) * 1024;
      xnA = xp[rA]; xnB = xp[rB];
    }
    const uint4* hb = (const uint4*)(hbuf + (size_t)(t & 1) * 128);
    float a0 = 0.0f, a1 = 0.0f;
#pragma unroll
    for (int q = 0; q < 24; ++q) {
      uint4 hv = hb[q];
      h2 hx = bch2(hv.x), hy = bch2(hv.y), hz = bch2(hv.z), hw = bch2(hv.w);
      a0 = fdot2f(w0[4 * q], hx, a0); a0 = fdot2f(w0[4 * q + 1], hy, a0);
      a0 = fdot2f(w0[4 * q + 2], hz, a0); a0 = fdot2f(w0[4 * q + 3], hw, a0);
      a1 = fdot2f(w1[4 * q], hx, a1); a1 = fdot2f(w1[4 * q + 1], hy, a1);
      a1 = fdot2f(w1[4 * q + 2], hz, a1); a1 = fdot2f(w1[4 * q + 3], hw, a1);
    }
#pragma unroll
    for (int qc = 0; qc < 8; ++qc) {
      uint4 hv = hb[24 + qc];
      h2 hx = bch2(hv.x), hy = bch2(hv.y), hz = bch2(hv.z), hw = bch2(hv.w);
      uint4 uA = wlds[qc * 1024 + rA];
      uint4 uB = wlds[qc * 1024 + rB];
      a0 = fdot2f(bch2(uA.x), hx, a0); a0 = fdot2f(bch2(uA.y), hy, a0);
      a0 = fdot2f(bch2(uA.z), hz, a0); a0 = fdot2f(bch2(uA.w), hw, a0);
      a1 = fdot2f(bch2(uB.x), hx, a1); a1 = fdot2f(bch2(uB.y), hy, a1);
      a1 = fdot2f(bch2(uB.z), hz, a1); a1 = fdot2f(bch2(uB.w), hw, a1);
    }
    a0 += xwA;
    a1 += xwB;
    float ev = sigf(a0) * tanhfast(a1);
    float ep = __shfl_xor(ev, 1);
    if (p == 1) {
      c = sigf(a0) * c + ep;
      float hv_ = sigf(a1) * tanhfast(c);
      ((_Float16*)(hbuf + (size_t)((t + 1) & 1) * 128))[u] = (_Float16)hv_;
      dec_out[((size_t)(b * 256 + t)) * 256 + u] = f2bf(hv_);
    }
    __syncthreads();
  }
}

// ---------------- pointer logits ----------------
__global__ void pointer_kernel(const float* __restrict__ pd, const float* __restrict__ penT,
                               const float* __restrict__ vptr, float* __restrict__ out) {
  __shared__ float pdr[256];
  __shared__ float vl[256];
  int bx = blockIdx.x;
  int b = bx >> 8;
  int tid = threadIdx.x;  // 256
  pdr[tid] = pd[(size_t)bx * 256 + tid];
  vl[tid] = vptr[tid];
  __syncthreads();
  const float* pT = penT + (size_t)b * 256 * 256;
  float acc = 0.0f;
  for (int h = 0; h < 256; ++h) {
    acc = fmaf(vl[h], tanhfast(pdr[h] + pT[(size_t)h * 256 + tid]), acc);
  }
  out[(size_t)bx * 256 + tid] = acc;
}

extern "C" void kernel_launch(void* const* d_in, const int* in_sizes, int n_in,
                              void* d_out, int out_size, void* d_ws, size_t ws_size,
                              hipStream_t stream) {
  const float* parts = (const float*)d_in[0];
  const int* ts = (const int*)d_in[1];
  const float* Wpe1 = (const float*)d_in[2];
  const float* bpe1 = (const float*)d_in[3];
  const float* Wpe2 = (const float*)d_in[4];
  const float* bpe2 = (const float*)d_in[5];
  const float* pos = (const float*)d_in[6];
  const float* Wqkv = (const float*)d_in[7];
  const float* bqkv = (const float*)d_in[8];
  const float* Wo = (const float*)d_in[9];
  const float* bo = (const float*)d_in[10];
  const float* ln1g = (const float*)d_in[11];
  const float* ln1b = (const float*)d_in[12];
  const float* W1f = (const float*)d_in[13];
  const float* b1f = (const float*)d_in[14];
  const float* W2f = (const float*)d_in[15];
  const float* b2f = (const float*)d_in[16];
  const float* ln2g = (const float*)d_in[17];
  const float* ln2b = (const float*)d_in[18];
  const float* Wih = (const float*)d_in[19];
  const float* Whh = (const float*)d_in[20];
  const float* bih = (const float*)d_in[21];
  const float* bhh = (const float*)d_in[22];
  const float* Wp = (const float*)d_in[23];
  const float* bp = (const float*)d_in[24];
  const float* vptr = (const float*)d_in[25];
  float* out = (float*)d_out;

  // ---- workspace layout (f32-slot units) ----
  float* W = (float*)d_ws;
  float* xbuf = W;                            // [2048,256] f32, live all
  ushort* xbf = (ushort*)(W + 524288);        // [2048,256] bf16, live all
  float* SCR = W + 786432;                    // 2097152 slots scratch
  float* qkvb = SCR;                          //   encoder: [2048,768] f32
  float* Xw = SCR;                            //   decoder: [2048,1024] f32
  float* pdb = SCR;                           //   tail: [2048,256] f32
  float* penTb = SCR + 1048576;               //   tail: [8,256,256] f32 transposed
  ushort* attbf = (ushort*)(W + 2883584);     // [2048,256] bf16 (encoder)
  ushort* ffbf = (ushort*)(W + 3145728);      // [2048,512] bf16 (encoder)
  ushort* dec_outbf = (ushort*)(W + 3407872); //   decoder: [2048,256] bf16
  ushort* wqkvbf = (ushort*)(W + 3670016);    // 589824 bf16
  ushort* wobf   = (ushort*)(W + 3964928);    // 196608
  ushort* w1fbf  = (ushort*)(W + 4063232);    // 393216
  ushort* w2fbf  = (ushort*)(W + 4259840);    // 393216
  ushort* wihbf  = (ushort*)(W + 4456448);    // 262144
  ushort* wpbf   = (ushort*)(W + 4587520);    // 65536

  const int attnLDS = (256 * 33 + 32 * 33 + 32 * 257) * 4;  // 70912 B
  const int scan512LDS = 131072 + 1024;                     // 132096 B
  hipFuncSetAttribute((const void*)attn_kernel, hipFuncAttributeMaxDynamicSharedMemorySize, attnLDS);
  hipFuncSetAttribute((const void*)lstm_scan512, hipFuncAttributeMaxDynamicSharedMemorySize, scan512LDS);

  convert_all<<<7424, 256, 0, stream>>>(Wqkv, wqkvbf, Wo, wobf, W1f, w1fbf,
                                        W2f, w2fbf, Wih, wihbf, Wp, wpbf);

  part_encoder<<<2048, 128, 0, stream>>>(parts, Wpe1, bpe1, Wpe2, bpe2, pos, xbuf, xbf);
  for (int l = 0; l < 3; ++l) {
    gemm_bf16<0, 0, 0><<<dim3(12, 128), 64, 0, stream>>>(
        xbf, wqkvbf + (size_t)l * 196608, bqkv + l * 768, nullptr, qkvb, 768, 256, nullptr);
    attn_kernel<<<dim3(8, 8, 8), 256, attnLDS, stream>>>(qkvb, attbf);
    gemm_ln<<<128, 256, 0, stream>>>(attbf, wobf + (size_t)l * 65536, bo + l * 256,
                                     xbuf, ln1g + l * 256, ln1b + l * 256, xbf, 256);
    gemm_bf16<1, 1, 0><<<dim3(8, 128), 64, 0, stream>>>(
        xbf, w1fbf + (size_t)l * 131072, b1f + l * 512, nullptr, ffbf, 512, 256, nullptr);
    gemm_ln<<<128, 256, 0, stream>>>(ffbf, w2fbf + (size_t)l * 131072, b2f + l * 256,
                                     xbuf, ln2g + l * 256, ln2b + l * 256, xbf, 512);
  }
  // Wih GEMM with fused teacher-forcing gather (A rows indexed via ts)
  gemm_bf16<0, 0, 1><<<dim3(16, 128), 64, 0, stream>>>(
      xbf, wihbf, bih, bhh, Xw, 1024, 256, ts);
  lstm_scan512<<<8, 512, scan512LDS, stream>>>(Xw, Whh, dec_outbf);
  gemm_bf16<0, 0, 0><<<dim3(4, 128), 64, 0, stream>>>(
      dec_outbf, wpbf, bp, nullptr, pdb, 256, 256, nullptr);
  gemm_bf16<0, 3, 0><<<dim3(4, 128), 64, 0, stream>>>(
      xbf, wpbf, bp, nullptr, penTb, 256, 256, nullptr);
  pointer_kernel<<<2048, 256, 0, stream>>>(pdb, penTb, vptr, out);
}

// Round 17
// 784.766 us; speedup vs baseline: 1.0537x; 1.0537x over previous
//
#include <hip/hip_runtime.h>
#include <cstdint>
#include <cstddef>

// LESSON (R13/R14): __has_builtin(__builtin_amdgcn_*) is FALSE in hipcc's HOST
// pass — never use it to select kernel launches host-side.

typedef _Float16 h2 __attribute__((ext_vector_type(2)));
typedef short bf16x8 __attribute__((ext_vector_type(8)));
typedef float f32x4 __attribute__((ext_vector_type(4)));

__device__ __forceinline__ float sigf(float x) { return 1.0f / (1.0f + __expf(-x)); }
__device__ __forceinline__ float tanhfast(float x) {
  float e = __expf(-2.0f * fabsf(x));
  float t = (1.0f - e) / (1.0f + e);
  return copysignf(t, x);
}
__device__ __forceinline__ h2 bch2(unsigned int u) { return __builtin_bit_cast(h2, u); }
__device__ __forceinline__ unsigned short f2bf(float f) {
  unsigned int u = __float_as_uint(f);
  u = (u + 0x7fffu + ((u >> 16) & 1u)) >> 16;
  return (unsigned short)u;
}

__device__ __forceinline__ float fdot2f(h2 a, h2 b, float c) {
#if __has_builtin(__builtin_amdgcn_fdot2)
  return __builtin_amdgcn_fdot2(a, b, c, false);
#else
  return fmaf((float)a.x, (float)b.x, fmaf((float)a.y, (float)b.y, c));
#endif
}

// ---------------- fused weight conversions (1 launch): bf16 for GEMMs, f16 Whh --
__global__ void convert_all(const float* __restrict__ s0, ushort* __restrict__ d0,
                            const float* __restrict__ s1, ushort* __restrict__ d1,
                            const float* __restrict__ s2, ushort* __restrict__ d2,
                            const float* __restrict__ s3, ushort* __restrict__ d3,
                            const float* __restrict__ s4, ushort* __restrict__ d4,
                            const float* __restrict__ s5, ushort* __restrict__ d5,
                            const float* __restrict__ s6, ushort* __restrict__ d6) {
  int i = blockIdx.x * 256 + threadIdx.x;
  if (i < 589824) { d0[i] = f2bf(s0[i]); return; }
  i -= 589824;
  if (i < 196608) { d1[i] = f2bf(s1[i]); return; }
  i -= 196608;
  if (i < 393216) { d2[i] = f2bf(s2[i]); return; }
  i -= 393216;
  if (i < 393216) { d3[i] = f2bf(s3[i]); return; }
  i -= 393216;
  if (i < 262144) { d4[i] = f2bf(s4[i]); return; }
  i -= 262144;
  if (i < 65536) { d5[i] = f2bf(s5[i]); return; }
  i -= 65536;
  if (i < 262144) d6[i] = __builtin_bit_cast(unsigned short, (_Float16)s6[i]);
}

// ---------------- part encoder ----------------
__global__ void part_encoder(const float* __restrict__ parts, const float* __restrict__ Wpe1,
                             const float* __restrict__ bpe1, const float* __restrict__ Wpe2,
                             const float* __restrict__ bpe2, const float* __restrict__ pos,
                             float* __restrict__ x, ushort* __restrict__ xb) {
  __shared__ float prow[16];
  __shared__ float pe1[128];
  int row = blockIdx.x;
  int s = row & 255;
  int tid = threadIdx.x;  // 128
  if (tid < 16) prow[tid] = parts[row * 16 + tid];
  __syncthreads();
  float a = bpe1[tid];
#pragma unroll
  for (int k = 0; k < 16; ++k) a = fmaf(prow[k], Wpe1[tid * 16 + k], a);
  pe1[tid] = fmaxf(a, 0.0f);
  __syncthreads();
  float a2 = bpe2[tid];
  for (int k = 0; k < 128; ++k) a2 = fmaf(pe1[k], Wpe2[tid * 128 + k], a2);
  x[(size_t)row * 256 + tid] = a2;
  xb[(size_t)row * 256 + tid] = f2bf(a2);
  if (tid < 64) {
    float p = pos[s * 64 + tid];
    x[(size_t)row * 256 + 128 + tid] = p;
    xb[(size_t)row * 256 + 128 + tid] = f2bf(p);
    x[(size_t)row * 256 + 192 + tid] = 0.0f;
    xb[(size_t)row * 256 + 192 + tid] = 0;
  }
}

// ---------------- MFMA bf16 GEMM, 1-wave blocks (16 rows x 64 cols) ------------
template <int ACT, int OUT, int GATHER>
__global__ __launch_bounds__(64) void gemm_bf16(
    const ushort* __restrict__ A, const ushort* __restrict__ Wt,
    const float* __restrict__ bias1, const float* __restrict__ bias2,
    void* __restrict__ Cout, int N, int K, const int* __restrict__ ts) {
  int lane = threadIdx.x;          // 0..63
  int m0 = blockIdx.y * 16;
  int n0 = blockIdx.x * 64;
  int r15 = lane & 15;
  int kg = lane >> 4;
  f32x4 acc0 = {0.f, 0.f, 0.f, 0.f}, acc1 = acc0, acc2 = acc0, acc3 = acc0;
  const ushort* arow;
  bool zeroA = false;
  if (GATHER) {
    int m = m0 + r15;
    int t = m >> 3, b = m & 7;
    if (t == 0) { zeroA = true; arow = A; }
    else {
      int sidx = ts[b * 256 + t - 1];
      arow = A + (size_t)(b * 256 + sidx) * 256 + kg * 8;
    }
  } else {
    arow = A + (size_t)(m0 + r15) * K + kg * 8;
  }
  const ushort* w0 = Wt + (size_t)(n0 + r15) * K + kg * 8;
  const ushort* w1 = w0 + (size_t)16 * K;
  const ushort* w2 = w0 + (size_t)32 * K;
  const ushort* w3 = w0 + (size_t)48 * K;
  for (int k0 = 0; k0 < K; k0 += 32) {
    bf16x8 af;
    if (GATHER && zeroA) af = (bf16x8){0, 0, 0, 0, 0, 0, 0, 0};
    else af = *(const bf16x8*)(arow + k0);
    bf16x8 b0 = *(const bf16x8*)(w0 + k0);
    bf16x8 b1 = *(const bf16x8*)(w1 + k0);
    bf16x8 b2 = *(const bf16x8*)(w2 + k0);
    bf16x8 b3 = *(const bf16x8*)(w3 + k0);
    acc0 = __builtin_amdgcn_mfma_f32_16x16x32_bf16(af, b0, acc0, 0, 0, 0);
    acc1 = __builtin_amdgcn_mfma_f32_16x16x32_bf16(af, b1, acc1, 0, 0, 0);
    acc2 = __builtin_amdgcn_mfma_f32_16x16x32_bf16(af, b2, acc2, 0, 0, 0);
    acc3 = __builtin_amdgcn_mfma_f32_16x16x32_bf16(af, b3, acc3, 0, 0, 0);
  }
#pragma unroll
  for (int nn = 0; nn < 4; ++nn) {
    f32x4 a = (nn == 0) ? acc0 : (nn == 1) ? acc1 : (nn == 2) ? acc2 : acc3;
    int n = n0 + nn * 16 + r15;
    float bsum = bias1[n] + (bias2 ? bias2[n] : 0.0f);
#pragma unroll
    for (int r = 0; r < 4; ++r) {
      int m = m0 + kg * 4 + r;
      float v = a[r] + bsum;
      if (ACT == 1) v = fmaxf(v, 0.0f);
      if (OUT == 1)
        ((ushort*)Cout)[(size_t)m * N + n] = f2bf(v);
      else
        ((float*)Cout)[(size_t)m * N + n] = v;
    }
  }
}

// ---------------- decoder tail: pd (z=0) + penT (z=1) in ONE dispatch ----------
__global__ __launch_bounds__(64) void gemm_tail(
    const ushort* __restrict__ dec, const ushort* __restrict__ xbf,
    const ushort* __restrict__ Wt, const float* __restrict__ bias1,
    float* __restrict__ pdb, float* __restrict__ penT) {
  int z = blockIdx.z;
  const ushort* A = z ? xbf : dec;
  int lane = threadIdx.x;
  int m0 = blockIdx.y * 16;
  int n0 = blockIdx.x * 64;
  int r15 = lane & 15;
  int kg = lane >> 4;
  f32x4 acc0 = {0.f, 0.f, 0.f, 0.f}, acc1 = acc0, acc2 = acc0, acc3 = acc0;
  const ushort* arow = A + (size_t)(m0 + r15) * 256 + kg * 8;
  const ushort* w0 = Wt + (size_t)(n0 + r15) * 256 + kg * 8;
  const ushort* w1 = w0 + (size_t)16 * 256;
  const ushort* w2 = w0 + (size_t)32 * 256;
  const ushort* w3 = w0 + (size_t)48 * 256;
  for (int k0 = 0; k0 < 256; k0 += 32) {
    bf16x8 af = *(const bf16x8*)(arow + k0);
    bf16x8 b0 = *(const bf16x8*)(w0 + k0);
    bf16x8 b1 = *(const bf16x8*)(w1 + k0);
    bf16x8 b2 = *(const bf16x8*)(w2 + k0);
    bf16x8 b3 = *(const bf16x8*)(w3 + k0);
    acc0 = __builtin_amdgcn_mfma_f32_16x16x32_bf16(af, b0, acc0, 0, 0, 0);
    acc1 = __builtin_amdgcn_mfma_f32_16x16x32_bf16(af, b1, acc1, 0, 0, 0);
    acc2 = __builtin_amdgcn_mfma_f32_16x16x32_bf16(af, b2, acc2, 0, 0, 0);
    acc3 = __builtin_amdgcn_mfma_f32_16x16x32_bf16(af, b3, acc3, 0, 0, 0);
  }
#pragma unroll
  for (int nn = 0; nn < 4; ++nn) {
    f32x4 a = (nn == 0) ? acc0 : (nn == 1) ? acc1 : (nn == 2) ? acc2 : acc3;
    int n = n0 + nn * 16 + r15;
    float bsum = bias1[n];
    if (z == 0) {
#pragma unroll
      for (int r = 0; r < 4; ++r)
        pdb[(size_t)(m0 + kg * 4 + r) * 256 + n] = a[r] + bsum;
    } else {
      int b = m0 >> 8;
      int mloc = (m0 & 255) + kg * 4;
      float4 o4 = {a[0] + bsum, a[1] + bsum, a[2] + bsum, a[3] + bsum};
      *(float4*)&penT[((size_t)(b * 256 + n)) * 256 + mloc] = o4;
    }
  }
}

// ---------------- fused GEMM (N=256) + residual LayerNorm ----------------
__global__ __launch_bounds__(256) void gemm_ln(
    const ushort* __restrict__ A, const ushort* __restrict__ Wt,
    const float* __restrict__ bias1, float* __restrict__ x,
    const float* __restrict__ g, const float* __restrict__ bt,
    ushort* __restrict__ xb, int K) {
  __shared__ float osm[16][257];
  int tid = threadIdx.x;
  int w = tid >> 6, lane = tid & 63;
  int m0 = blockIdx.x * 16;
  int n0 = w * 64;
  int r15 = lane & 15, kg = lane >> 4;
  f32x4 acc0 = {0.f, 0.f, 0.f, 0.f}, acc1 = acc0, acc2 = acc0, acc3 = acc0;
  const ushort* arow = A + (size_t)(m0 + r15) * K + kg * 8;
  const ushort* w0 = Wt + (size_t)(n0 + r15) * K + kg * 8;
  const ushort* w1 = w0 + (size_t)16 * K;
  const ushort* w2 = w0 + (size_t)32 * K;
  const ushort* w3 = w0 + (size_t)48 * K;
  for (int k0 = 0; k0 < K; k0 += 32) {
    bf16x8 af = *(const bf16x8*)(arow + k0);
    bf16x8 b0 = *(const bf16x8*)(w0 + k0);
    bf16x8 b1 = *(const bf16x8*)(w1 + k0);
    bf16x8 b2 = *(const bf16x8*)(w2 + k0);
    bf16x8 b3 = *(const bf16x8*)(w3 + k0);
    acc0 = __builtin_amdgcn_mfma_f32_16x16x32_bf16(af, b0, acc0, 0, 0, 0);
    acc1 = __builtin_amdgcn_mfma_f32_16x16x32_bf16(af, b1, acc1, 0, 0, 0);
    acc2 = __builtin_amdgcn_mfma_f32_16x16x32_bf16(af, b2, acc2, 0, 0, 0);
    acc3 = __builtin_amdgcn_mfma_f32_16x16x32_bf16(af, b3, acc3, 0, 0, 0);
  }
#pragma unroll
  for (int nn = 0; nn < 4; ++nn) {
    f32x4 a = (nn == 0) ? acc0 : (nn == 1) ? acc1 : (nn == 2) ? acc2 : acc3;
    int col = n0 + nn * 16 + r15;
    float bsum = bias1[col];
#pragma unroll
    for (int r = 0; r < 4; ++r) osm[kg * 4 + r][col] = a[r] + bsum;
  }
  __syncthreads();
  int row = tid >> 4, j = tid & 15;
  size_t xoff = (size_t)(m0 + row) * 256 + j * 16;
  float4 xv0 = *(const float4*)&x[xoff];
  float4 xv1 = *(const float4*)&x[xoff + 4];
  float4 xv2 = *(const float4*)&x[xoff + 8];
  float4 xv3 = *(const float4*)&x[xoff + 12];
  float e0 = xv0.x + osm[row][j * 16 + 0], e1 = xv0.y + osm[row][j * 16 + 1];
  float e2 = xv0.z + osm[row][j * 16 + 2], e3 = xv0.w + osm[row][j * 16 + 3];
  float e4 = xv1.x + osm[row][j * 16 + 4], e5 = xv1.y + osm[row][j * 16 + 5];
  float e6 = xv1.z + osm[row][j * 16 + 6], e7 = xv1.w + osm[row][j * 16 + 7];
  float e8 = xv2.x + osm[row][j * 16 + 8], e9 = xv2.y + osm[row][j * 16 + 9];
  float e10 = xv2.z + osm[row][j * 16 + 10], e11 = xv2.w + osm[row][j * 16 + 11];
  float e12 = xv3.x + osm[row][j * 16 + 12], e13 = xv3.y + osm[row][j * 16 + 13];
  float e14 = xv3.z + osm[row][j * 16 + 14], e15 = xv3.w + osm[row][j * 16 + 15];
  float s = ((e0 + e1) + (e2 + e3)) + ((e4 + e5) + (e6 + e7)) +
            ((e8 + e9) + (e10 + e11)) + ((e12 + e13) + (e14 + e15));
  float q = ((e0 * e0 + e1 * e1) + (e2 * e2 + e3 * e3)) +
            ((e4 * e4 + e5 * e5) + (e6 * e6 + e7 * e7)) +
            ((e8 * e8 + e9 * e9) + (e10 * e10 + e11 * e11)) +
            ((e12 * e12 + e13 * e13) + (e14 * e14 + e15 * e15));
#pragma unroll
  for (int off = 1; off <= 8; off <<= 1) {
    s += __shfl_xor(s, off);
    q += __shfl_xor(q, off);
  }
  float mean = s * (1.0f / 256.0f);
  float var = q * (1.0f / 256.0f) - mean * mean;
  float inv = rsqrtf(var + 1e-5f);
  const float* gp = g + j * 16;
  const float* bp2 = bt + j * 16;
  float y0 = (e0 - mean) * inv * gp[0] + bp2[0];
  float y1 = (e1 - mean) * inv * gp[1] + bp2[1];
  float y2 = (e2 - mean) * inv * gp[2] + bp2[2];
  float y3 = (e3 - mean) * inv * gp[3] + bp2[3];
  float y4 = (e4 - mean) * inv * gp[4] + bp2[4];
  float y5 = (e5 - mean) * inv * gp[5] + bp2[5];
  float y6 = (e6 - mean) * inv * gp[6] + bp2[6];
  float y7 = (e7 - mean) * inv * gp[7] + bp2[7];
  float y8 = (e8 - mean) * inv * gp[8] + bp2[8];
  float y9 = (e9 - mean) * inv * gp[9] + bp2[9];
  float y10 = (e10 - mean) * inv * gp[10] + bp2[10];
  float y11 = (e11 - mean) * inv * gp[11] + bp2[11];
  float y12 = (e12 - mean) * inv * gp[12] + bp2[12];
  float y13 = (e13 - mean) * inv * gp[13] + bp2[13];
  float y14 = (e14 - mean) * inv * gp[14] + bp2[14];
  float y15 = (e15 - mean) * inv * gp[15] + bp2[15];
  *(float4*)&x[xoff] = make_float4(y0, y1, y2, y3);
  *(float4*)&x[xoff + 4] = make_float4(y4, y5, y6, y7);
  *(float4*)&x[xoff + 8] = make_float4(y8, y9, y10, y11);
  *(float4*)&x[xoff + 12] = make_float4(y12, y13, y14, y15);
  ushort4 u0, u1, u2, u3;
  u0.x = f2bf(y0); u0.y = f2bf(y1); u0.z = f2bf(y2); u0.w = f2bf(y3);
  u1.x = f2bf(y4); u1.y = f2bf(y5); u1.z = f2bf(y6); u1.w = f2bf(y7);
  u2.x = f2bf(y8); u2.y = f2bf(y9); u2.z = f2bf(y10); u2.w = f2bf(y11);
  u3.x = f2bf(y12); u3.y = f2bf(y13); u3.z = f2bf(y14); u3.w = f2bf(y15);
  *(ushort4*)&xb[xoff] = u0;
  *(ushort4*)&xb[xoff + 4] = u1;
  *(ushort4*)&xb[xoff + 8] = u2;
  *(ushort4*)&xb[xoff + 12] = u3;
}

// ---------------- attention (f32 in, bf16 out) ----------------
__global__ void attn_kernel(const float* __restrict__ qkv, ushort* __restrict__ attout) {
  extern __shared__ float sm[];
  float* kl = sm;
  float* ql = sm + 256 * 33;
  float* sc = sm + 256 * 33 + 32 * 33;
  int qt = blockIdx.x, h = blockIdx.y, b = blockIdx.z;
  int tid = threadIdx.x;  // 256
  {
    int j = tid;
    const float* src = qkv + (size_t)(b * 256 + j) * 768 + 256 + h * 32;
#pragma unroll
    for (int d = 0; d < 32; d += 4) {
      float4 v = *(const float4*)(src + d);
      kl[j * 33 + d] = v.x; kl[j * 33 + d + 1] = v.y; kl[j * 33 + d + 2] = v.z; kl[j * 33 + d + 3] = v.w;
    }
  }
  {
    int i = tid >> 3, d4 = (tid & 7) * 4;
    const float* src = qkv + (size_t)(b * 256 + qt * 32 + i) * 768 + h * 32;
    float4 v = *(const float4*)(src + d4);
    ql[i * 33 + d4] = v.x; ql[i * 33 + d4 + 1] = v.y; ql[i * 33 + d4 + 2] = v.z; ql[i * 33 + d4 + 3] = v.w;
  }
  __syncthreads();
  int i = tid >> 3, c = tid & 7;
  const float scale = 0.17677669529663687f;
  float sv[32];
  float mx = -1e30f;
  for (int jj = 0; jj < 32; ++jj) {
    int j = jj * 8 + c;
    float s = 0.0f;
#pragma unroll
    for (int d = 0; d < 32; ++d) s = fmaf(ql[i * 33 + d], kl[j * 33 + d], s);
    s *= scale;
    sv[jj] = s;
    mx = fmaxf(mx, s);
  }
  mx = fmaxf(mx, __shfl_xor(mx, 1));
  mx = fmaxf(mx, __shfl_xor(mx, 2));
  mx = fmaxf(mx, __shfl_xor(mx, 4));
  float sum = 0.0f;
  for (int jj = 0; jj < 32; ++jj) {
    float p = __expf(sv[jj] - mx);
    sc[i * 257 + jj * 8 + c] = p;
    sum += p;
  }
  sum += __shfl_xor(sum, 1);
  sum += __shfl_xor(sum, 2);
  sum += __shfl_xor(sum, 4);
  float inv = 1.0f / sum;
  __syncthreads();
  float a0 = 0, a1 = 0, a2 = 0, a3 = 0;
  int d0 = c * 4;
  const float* vbase = qkv + 512 + h * 32 + d0;
  for (int j = 0; j < 256; ++j) {
    float p = sc[i * 257 + j];
    float4 v = *(const float4*)(vbase + (size_t)(b * 256 + j) * 768);
    a0 = fmaf(p, v.x, a0); a1 = fmaf(p, v.y, a1); a2 = fmaf(p, v.z, a2); a3 = fmaf(p, v.w, a3);
  }
  int orow = b * 256 + qt * 32 + i;
  ushort4 o4;
  o4.x = f2bf(a0 * inv); o4.y = f2bf(a1 * inv); o4.z = f2bf(a2 * inv); o4.w = f2bf(a3 * inv);
  *(ushort4*)&attout[(size_t)orow * 256 + h * 32 + d0] = o4;
}

// ---------------- LSTM scan v512 (f16 Whh source; single-CU storage floor) -----
__global__ __attribute__((amdgpu_flat_work_group_size(512, 512), amdgpu_waves_per_eu(1, 1)))
void lstm_scan512(const float* __restrict__ Xw, const ushort* __restrict__ WhhH,
                  ushort* __restrict__ dec_out) {
  extern __shared__ char smem[];
  uint4* wlds = (uint4*)smem;                 // [8][1024] uint4 = 128 KB
  h2* hbuf = (h2*)(smem + 131072);            // [2][128] h2
  int b = blockIdx.x;
  int t0 = threadIdx.x;        // 0..511
  int u = t0 >> 1, p = t0 & 1;
  int rA = u + 256 * p;
  int rB = u + 512 + 256 * p;

  h2 w0[96], w1[96];
  {
    const uint4* sA = (const uint4*)(WhhH + (size_t)rA * 256);  // 32 uint4/row (f16)
    const uint4* sB = (const uint4*)(WhhH + (size_t)rB * 256);
#pragma unroll
    for (int k = 0; k < 24; ++k) {  // cols 0..191 -> regs
      uint4 q = sA[k];
      w0[4 * k] = bch2(q.x); w0[4 * k + 1] = bch2(q.y);
      w0[4 * k + 2] = bch2(q.z); w0[4 * k + 3] = bch2(q.w);
    }
#pragma unroll
    for (int k = 0; k < 24; ++k) {
      uint4 q = sB[k];
      w1[4 * k] = bch2(q.x); w1[4 * k + 1] = bch2(q.y);
      w1[4 * k + 2] = bch2(q.z); w1[4 * k + 3] = bch2(q.w);
    }
#pragma unroll
    for (int qc = 0; qc < 8; ++qc) {  // cols 192..255 -> LDS
      wlds[qc * 1024 + rA] = sA[24 + qc];
      wlds[qc * 1024 + rB] = sB[24 + qc];
    }
  }
  if (t0 < 128) ((uint4*)hbuf)[t0 & 63] = make_uint4(0, 0, 0, 0);
  float c = 0.0f;
  float xnA = Xw[(size_t)b * 1024 + rA];
  float xnB = Xw[(size_t)b * 1024 + rB];
  __syncthreads();

  for (int t = 0; t < 256; ++t) {
    float xwA = xnA, xwB = xnB;
    if (t < 255) {
      const float* xp = Xw + (size_t)((t + 1) * 8 + b) * 1024;
      xnA = xp[rA]; xnB = xp[rB];
    }
    const uint4* hb = (const uint4*)(hbuf + (size_t)(t & 1) * 128);
    float a0 = 0.0f, a1 = 0.0f;
#pragma unroll
    for (int q = 0; q < 24; ++q) {
      uint4 hv = hb[q];
      h2 hx = bch2(hv.x), hy = bch2(hv.y), hz = bch2(hv.z), hw = bch2(hv.w);
      a0 = fdot2f(w0[4 * q], hx, a0); a0 = fdot2f(w0[4 * q + 1], hy, a0);
      a0 = fdot2f(w0[4 * q + 2], hz, a0); a0 = fdot2f(w0[4 * q + 3], hw, a0);
      a1 = fdot2f(w1[4 * q], hx, a1); a1 = fdot2f(w1[4 * q + 1], hy, a1);
      a1 = fdot2f(w1[4 * q + 2], hz, a1); a1 = fdot2f(w1[4 * q + 3], hw, a1);
    }
#pragma unroll
    for (int qc = 0; qc < 8; ++qc) {
      uint4 hv = hb[24 + qc];
      h2 hx = bch2(hv.x), hy = bch2(hv.y), hz = bch2(hv.z), hw = bch2(hv.w);
      uint4 uA = wlds[qc * 1024 + rA];
      uint4 uB = wlds[qc * 1024 + rB];
      a0 = fdot2f(bch2(uA.x), hx, a0); a0 = fdot2f(bch2(uA.y), hy, a0);
      a0 = fdot2f(bch2(uA.z), hz, a0); a0 = fdot2f(bch2(uA.w), hw, a0);
      a1 = fdot2f(bch2(uB.x), hx, a1); a1 = fdot2f(bch2(uB.y), hy, a1);
      a1 = fdot2f(bch2(uB.z), hz, a1); a1 = fdot2f(bch2(uB.w), hw, a1);
    }
    a0 += xwA;
    a1 += xwB;
    float ev = sigf(a0) * tanhfast(a1);
    float ep = __shfl_xor(ev, 1);
    if (p == 1) {
      c = sigf(a0) * c + ep;
      float hv_ = sigf(a1) * tanhfast(c);
      ((_Float16*)(hbuf + (size_t)((t + 1) & 1) * 128))[u] = (_Float16)hv_;
      dec_out[((size_t)(b * 256 + t)) * 256 + u] = f2bf(hv_);
    }
    __syncthreads();
  }
}

// ---------------- pointer logits ----------------
__global__ void pointer_kernel(const float* __restrict__ pd, const float* __restrict__ penT,
                               const float* __restrict__ vptr, float* __restrict__ out) {
  __shared__ float pdr[256];
  __shared__ float vl[256];
  int bx = blockIdx.x;
  int b = bx >> 8;
  int tid = threadIdx.x;  // 256
  pdr[tid] = pd[(size_t)bx * 256 + tid];
  vl[tid] = vptr[tid];
  __syncthreads();
  const float* pT = penT + (size_t)b * 256 * 256;
  float acc = 0.0f;
  for (int h = 0; h < 256; ++h) {
    acc = fmaf(vl[h], tanhfast(pdr[h] + pT[(size_t)h * 256 + tid]), acc);
  }
  out[(size_t)bx * 256 + tid] = acc;
}

extern "C" void kernel_launch(void* const* d_in, const int* in_sizes, int n_in,
                              void* d_out, int out_size, void* d_ws, size_t ws_size,
                              hipStream_t stream) {
  const float* parts = (const float*)d_in[0];
  const int* ts = (const int*)d_in[1];
  const float* Wpe1 = (const float*)d_in[2];
  const float* bpe1 = (const float*)d_in[3];
  const float* Wpe2 = (const float*)d_in[4];
  const float* bpe2 = (const float*)d_in[5];
  const float* pos = (const float*)d_in[6];
  const float* Wqkv = (const float*)d_in[7];
  const float* bqkv = (const float*)d_in[8];
  const float* Wo = (const float*)d_in[9];
  const float* bo = (const float*)d_in[10];
  const float* ln1g = (const float*)d_in[11];
  const float* ln1b = (const float*)d_in[12];
  const float* W1f = (const float*)d_in[13];
  const float* b1f = (const float*)d_in[14];
  const float* W2f = (const float*)d_in[15];
  const float* b2f = (const float*)d_in[16];
  const float* ln2g = (const float*)d_in[17];
  const float* ln2b = (const float*)d_in[18];
  const float* Wih = (const float*)d_in[19];
  const float* Whh = (const float*)d_in[20];
  const float* bih = (const float*)d_in[21];
  const float* bhh = (const float*)d_in[22];
  const float* Wp = (const float*)d_in[23];
  const float* bp = (const float*)d_in[24];
  const float* vptr = (const float*)d_in[25];
  float* out = (float*)d_out;

  // ---- workspace layout (f32-slot units); end = 4751360 slots = 19 MB ----
  float* W = (float*)d_ws;
  float* xbuf = W;                            // [2048,256] f32, live all
  ushort* xbf = (ushort*)(W + 524288);        // [2048,256] bf16, live all
  float* SCR = W + 786432;                    // 2097152 slots scratch
  float* qkvb = SCR;                          //   encoder: [2048,768] f32
  float* Xw = SCR;                            //   decoder: [2048,1024] f32
  float* pdb = SCR;                           //   tail: [2048,256] f32
  float* penTb = SCR + 1048576;               //   tail: [8,256,256] f32 transposed
  ushort* attbf = (ushort*)(W + 2883584);     // [2048,256] bf16 (encoder)
  ushort* ffbf = (ushort*)(W + 3145728);      // [2048,512] bf16 (encoder)
  ushort* dec_outbf = (ushort*)(W + 3407872); //   decoder: [2048,256] bf16
  ushort* wqkvbf = (ushort*)(W + 3670016);    // 589824 bf16
  ushort* wobf   = (ushort*)(W + 3964928);    // 196608
  ushort* w1fbf  = (ushort*)(W + 4063232);    // 393216
  ushort* w2fbf  = (ushort*)(W + 4259840);    // 393216
  ushort* wihbf  = (ushort*)(W + 4456448);    // 262144
  ushort* wpbf   = (ushort*)(W + 4587520);    // 65536
  ushort* whhh   = (ushort*)(W + 4620288);    // 262144 f16 (131072 slots)

  const int attnLDS = (256 * 33 + 32 * 33 + 32 * 257) * 4;  // 70912 B
  const int scan512LDS = 131072 + 1024;                     // 132096 B
  hipFuncSetAttribute((const void*)attn_kernel, hipFuncAttributeMaxDynamicSharedMemorySize, attnLDS);
  hipFuncSetAttribute((const void*)lstm_scan512, hipFuncAttributeMaxDynamicSharedMemorySize, scan512LDS);

  // fused weight conversion (bf16 GEMM weights + f16 Whh), 1 launch
  convert_all<<<8448, 256, 0, stream>>>(Wqkv, wqkvbf, Wo, wobf, W1f, w1fbf,
                                        W2f, w2fbf, Wih, wihbf, Wp, wpbf, Whh, whhh);

  part_encoder<<<2048, 128, 0, stream>>>(parts, Wpe1, bpe1, Wpe2, bpe2, pos, xbuf, xbf);
  for (int l = 0; l < 3; ++l) {
    gemm_bf16<0, 0, 0><<<dim3(12, 128), 64, 0, stream>>>(
        xbf, wqkvbf + (size_t)l * 196608, bqkv + l * 768, nullptr, qkvb, 768, 256, nullptr);
    attn_kernel<<<dim3(8, 8, 8), 256, attnLDS, stream>>>(qkvb, attbf);
    gemm_ln<<<128, 256, 0, stream>>>(attbf, wobf + (size_t)l * 65536, bo + l * 256,
                                     xbuf, ln1g + l * 256, ln1b + l * 256, xbf, 256);
    gemm_bf16<1, 1, 0><<<dim3(8, 128), 64, 0, stream>>>(
        xbf, w1fbf + (size_t)l * 131072, b1f + l * 512, nullptr, ffbf, 512, 256, nullptr);
    gemm_ln<<<128, 256, 0, stream>>>(ffbf, w2fbf + (size_t)l * 131072, b2f + l * 256,
                                     xbuf, ln2g + l * 256, ln2b + l * 256, xbf, 512);
  }
  gemm_bf16<0, 0, 1><<<dim3(16, 128), 64, 0, stream>>>(
      xbf, wihbf, bih, bhh, Xw, 1024, 256, ts);
  lstm_scan512<<<8, 512, scan512LDS, stream>>>(Xw, whhh, dec_outbf);
  gemm_tail<<<dim3(4, 128, 2), 64, 0, stream>>>(dec_outbf, xbf, wpbf, bp, pdb, penTb);
  pointer_kernel<<<2048, 256, 0, stream>>>(pdb, penTb, vptr, out);
}